// Round 1
// baseline (495.922 us; speedup 1.0000x reference)
//
#include <hip/hip_runtime.h>
#include <hip/hip_bf16.h>

// Problem constants
#define N_V   50000
#define CDIM  64
#define RAORD 40          // R*A = 5*8
#define KTOT  2624        // RA*C + C = 41*64
#define NOUT  512         // O*T = 8*64
#define NKB   41          // K chunks of 64
#define BM    128
#define BN    256

typedef short v8s __attribute__((ext_vector_type(8)));
typedef float v4f __attribute__((ext_vector_type(4)));
typedef unsigned short u16;

// LDS row stride in elements: 72 elems = 144 B = 36 dwords -> row*36 % 32 cycles
// through 8 bank groups -> 2-way conflict (free) for ds_read_b128 fragments.
#define LSTR 72

__device__ __forceinline__ u16 f2bf(float f) {
    unsigned u = __float_as_uint(f);
    return (u16)((u + 0x7FFFu + ((u >> 16) & 1u)) >> 16);   // RNE
}
__device__ __forceinline__ float bf2f(short s) {
    return __uint_as_float(((unsigned)(unsigned short)s) << 16);
}

// ---------- kernel 1: mesh_signal fp32 -> bf16 (6.4 MB, lives in L2/L3) ----------
__global__ void cast_ms(const float* __restrict__ ms, u16* __restrict__ msb) {
    int i = (blockIdx.x * 256 + threadIdx.x) * 4;   // grid exactly covers 3.2M
    float4 v = *reinterpret_cast<const float4*>(ms + i);
    ushort4 o;
    o.x = f2bf(v.x); o.y = f2bf(v.y); o.z = f2bf(v.z); o.w = f2bf(v.w);
    *reinterpret_cast<ushort4*>(msb + i) = o;
}

// ---------- kernel 2: combined weights W2[(o,t), k] (512 x 2624 bf16) ----------
// W2[j=o*64+t, m*64+c] = sum_{r,a} coeff[r,a,m] * nw[t, r, (a+o)%8, c]
// W2[j, 2560+c]        = cw[t, c]
__global__ void build_w2(const float* __restrict__ nw, const float* __restrict__ cw,
                         const float* __restrict__ coeff, u16* __restrict__ w2) {
    __shared__ float scoef[1600];
    __shared__ float snw[2560];
    int j = blockIdx.x;            // 0..511
    int o = j >> 6, t = j & 63;
    int tid = threadIdx.x;         // 256
    for (int l = tid; l < 1600; l += 256) scoef[l] = coeff[l];
    for (int l = tid; l < 2560; l += 256) {
        int ra = l >> 6, c = l & 63;
        int r = ra >> 3, a = ra & 7;
        snw[l] = nw[((t * 5 + r) * 8 + ((a + o) & 7)) * 64 + c];
    }
    __syncthreads();
    for (int l = tid; l < 2560; l += 256) {
        int m = l >> 6, c = l & 63;    // m wave-uniform, c = lane -> conflict-free
        float s = 0.f;
        #pragma unroll
        for (int ra = 0; ra < 40; ++ra)
            s += scoef[ra * 40 + m] * snw[ra * 64 + c];
        w2[(size_t)j * KTOT + l] = f2bf(s);
    }
    if (tid < 64) w2[(size_t)j * KTOT + 2560 + tid] = f2bf(cw[t * 64 + tid]);
}

// ---------- kernel 3: fused patch-operator + GEMM + bias + relu ----------
// out(50000 x 512) = relu( X(50000 x 2624) * W2^T + bias ), A-tile built on the fly.
__global__ __launch_bounds__(512, 4)
void gemm_fused(const float* __restrict__ bary, const u16* __restrict__ msb,
                const u16* __restrict__ w2, const float* __restrict__ bias,
                float* __restrict__ out) {
    __shared__ u16 At[BM * LSTR];   // 18,432 B
    __shared__ u16 Bt[BN * LSTR];   // 36,864 B

    int tid  = threadIdx.x;
    int lane = tid & 63, wave = tid >> 6;
    int l15  = lane & 15, q = lane >> 4;
    int wm   = wave >> 2, wn = wave & 3;          // 2 x 4 wave grid of 64x64 tiles
    int row0 = blockIdx.x * BM;
    int col0 = blockIdx.y * BN;

    v4f acc[4][4];
    #pragma unroll
    for (int mi = 0; mi < 4; ++mi)
        #pragma unroll
        for (int ni = 0; ni < 4; ++ni)
            acc[mi][ni] = (v4f){0.f, 0.f, 0.f, 0.f};

    // A-build mapping: thread -> (row 0..127, 16-col slab)
    int ar = tid >> 2;
    int ac = (tid & 3) * 16;
    int an = row0 + ar; if (an > N_V - 1) an = N_V - 1;   // tail rows: garbage, masked at store
    const float* bbase = bary + (size_t)an * 240;          // (N, 40, 3, 2)

    // B-stage mapping: thread -> (w2 row 0..255, 32-col half)
    int bj = tid >> 1;
    int bc = (tid & 1) * 32;
    const u16* wrow = w2 + (size_t)(col0 + bj) * KTOT + bc;

    for (int kb = 0; kb < NKB; ++kb) {
        __syncthreads();   // previous iter's fragment reads done

        // ---- stage B tile: 256 rows x 64 k (pure bf16 copy) ----
        {
            const u16* src = wrow + kb * 64;
            u16* dst = &Bt[bj * LSTR + bc];
            #pragma unroll
            for (int qq = 0; qq < 4; ++qq)
                *reinterpret_cast<v8s*>(dst + qq * 8) =
                    *reinterpret_cast<const v8s*>(src + qq * 8);
        }

        // ---- build A tile: barycentric gather-interp for k chunk kb ----
        u16* adst = &At[ar * LSTR + ac];
        if (kb < RAORD) {
            const float* bb = bbase + kb * 6;
            int  i0 = (int)bb[0]; float w0 = bb[1];
            int  i1 = (int)bb[2]; float w1 = bb[3];
            int  i2 = (int)bb[4]; float w2w = bb[5];
            const u16* g0 = msb + (size_t)i0 * 64 + ac;
            const u16* g1 = msb + (size_t)i1 * 64 + ac;
            const u16* g2 = msb + (size_t)i2 * 64 + ac;
            #pragma unroll
            for (int h = 0; h < 2; ++h) {
                v8s a0 = *reinterpret_cast<const v8s*>(g0 + h * 8);
                v8s a1 = *reinterpret_cast<const v8s*>(g1 + h * 8);
                v8s a2 = *reinterpret_cast<const v8s*>(g2 + h * 8);
                v8s r;
                #pragma unroll
                for (int e = 0; e < 8; ++e) {
                    float f = w0 * bf2f(a0[e]) + w1 * bf2f(a1[e]) + w2w * bf2f(a2[e]);
                    r[e] = (short)f2bf(f);
                }
                *reinterpret_cast<v8s*>(adst + h * 8) = r;
            }
        } else {
            // center chunk: A columns 2560..2623 = mesh_signal itself
            const u16* src = msb + (size_t)an * 64 + ac;
            *reinterpret_cast<v8s*>(adst)     = *reinterpret_cast<const v8s*>(src);
            *reinterpret_cast<v8s*>(adst + 8) = *reinterpret_cast<const v8s*>(src + 8);
        }
        __syncthreads();

        // ---- MFMA: 2 k-steps of 32 ----
        #pragma unroll
        for (int s = 0; s < 2; ++s) {
            v8s af[4], bfv[4];
            #pragma unroll
            for (int mi = 0; mi < 4; ++mi)
                af[mi] = *reinterpret_cast<const v8s*>(
                    &At[(wm * 64 + mi * 16 + l15) * LSTR + s * 32 + q * 8]);
            #pragma unroll
            for (int ni = 0; ni < 4; ++ni)
                bfv[ni] = *reinterpret_cast<const v8s*>(
                    &Bt[(wn * 64 + ni * 16 + l15) * LSTR + s * 32 + q * 8]);
            #pragma unroll
            for (int mi = 0; mi < 4; ++mi)
                #pragma unroll
                for (int ni = 0; ni < 4; ++ni)
                    acc[mi][ni] = __builtin_amdgcn_mfma_f32_16x16x32_bf16(
                        af[mi], bfv[ni], acc[mi][ni], 0, 0, 0);
        }
    }

    // ---- epilogue: + bias, relu, masked store ----
    float bv[4];
    #pragma unroll
    for (int ni = 0; ni < 4; ++ni) bv[ni] = bias[ni * 16 + l15];  // t = col & 63
    #pragma unroll
    for (int mi = 0; mi < 4; ++mi) {
        int rbase = row0 + wm * 64 + mi * 16 + q * 4;
        #pragma unroll
        for (int ni = 0; ni < 4; ++ni) {
            int cg = col0 + wn * 64 + ni * 16 + l15;
            #pragma unroll
            for (int rg = 0; rg < 4; ++rg) {
                int rr = rbase + rg;
                if (rr < N_V) {
                    float v = acc[mi][ni][rg] + bv[ni];
                    out[(size_t)rr * NOUT + cg] = v > 0.f ? v : 0.f;
                }
            }
        }
    }
}

extern "C" void kernel_launch(void* const* d_in, const int* in_sizes, int n_in,
                              void* d_out, int out_size, void* d_ws, size_t ws_size,
                              hipStream_t stream) {
    const float* ms    = (const float*)d_in[0];   // (50000, 64)
    const float* bary  = (const float*)d_in[1];   // (50000, 5, 8, 3, 2)
    const float* nw    = (const float*)d_in[2];   // (64, 5, 8, 64)
    const float* cw    = (const float*)d_in[3];   // (64, 1, 64)
    const float* bias  = (const float*)d_in[4];   // (64,)
    const float* coeff = (const float*)d_in[5];   // (5, 8, 40)
    float* out = (float*)d_out;

    u16* msb = (u16*)d_ws;                            // 3.2M bf16 = 6,400,000 B
    u16* w2  = (u16*)((char*)d_ws + 6400000);         // 512*2624 bf16 = 2,686,976 B

    cast_ms<<<3125, 256, 0, stream>>>(ms, msb);
    build_w2<<<512, 256, 0, stream>>>(nw, cw, coeff, w2);
    dim3 grid((N_V + BM - 1) / BM, NOUT / BN);        // (391, 2)
    gemm_fused<<<grid, 512, 0, stream>>>(bary, msb, w2, bias, out);
}